// Round 9
// baseline (394.647 us; speedup 1.0000x reference)
//
#include <hip/hip_runtime.h>

#define N_ATOMS 65536
#define AF      133
#define BT      147
#define HID     256
#define NNB     6
#define NM      2048

#define KI   160        // atom(133) padded
#define KB   32         // bond(14) padded
#define KP   256        // msg-side GEMMs (exact)
// LDS strides (elements)
#define LSI  168
#define LSB  40
#define LSP  264

typedef __attribute__((ext_vector_type(8))) short short8;
typedef __attribute__((ext_vector_type(4))) float f32x4;

__device__ __forceinline__ unsigned short f2bf(float f) {
    unsigned u = __builtin_bit_cast(unsigned, f);
    u += 0x7fffu + ((u >> 16) & 1u);
    return (unsigned short)(u >> 16);
}
__device__ __forceinline__ float bf2f(unsigned short s) {
    unsigned u = ((unsigned)s) << 16;
    return __builtin_bit_cast(float, u);
}

// ---------------------------------------------------------------------------
// k_prep_bond: weight transposes (bf16 [N][K]) + b_ih + bondsum gather.
// ---------------------------------------------------------------------------
__global__ __launch_bounds__(256) void k_prep_bond(const float* __restrict__ Wi,
                                                   const float* __restrict__ Wh,
                                                   const float* __restrict__ Wo,
                                                   const float* __restrict__ bi,
                                                   const float* __restrict__ bh,
                                                   const float* __restrict__ f_bonds,
                                                   const int* __restrict__ a2b,
                                                   unsigned short* __restrict__ Wi_t,
                                                   unsigned short* __restrict__ Wb_t,
                                                   unsigned short* __restrict__ Whm_t,
                                                   unsigned short* __restrict__ Woa_t,
                                                   unsigned short* __restrict__ Wom_t,
                                                   unsigned short* __restrict__ bondsum,
                                                   float* __restrict__ b_ih) {
    if (blockIdx.x < 256) {
        const int n = blockIdx.x;
        if (n == 0) b_ih[threadIdx.x] = bi[threadIdx.x] + bh[threadIdx.x];
        for (int k = threadIdx.x; k < KI; k += 256) {
            Wi_t[n * KI + k]  = f2bf(k < AF ? Wi[k * HID + n] : 0.f);
            Woa_t[n * KI + k] = f2bf(k < AF ? Wo[k * HID + n] : 0.f);
        }
        for (int k = threadIdx.x; k < KB; k += 256)
            Wb_t[n * KB + k] = f2bf(k < 14 ? Wh[(HID + k) * HID + n] : 0.f);
        for (int k = threadIdx.x; k < KP; k += 256) {
            Whm_t[n * KP + k] = f2bf(Wh[k * HID + n]);
            Wom_t[n * KP + k] = f2bf(Wo[(AF + k) * HID + n]);
        }
    } else {
        const int id   = (blockIdx.x - 256) * 256 + threadIdx.x;
        const int atom = id >> 4;
        const int c    = id & 15;
        float s = 0.f;
        if (c < 14) {
            const int* nb = &a2b[atom * NNB];
#pragma unroll
            for (int t = 0; t < NNB; ++t)
                s += f_bonds[(size_t)nb[t] * BT + (BT - 14) + c];
        }
        bondsum[atom * 32 + c]      = f2bf(s);
        bondsum[atom * 32 + 16 + c] = 0;
    }
}

// ---------------------------------------------------------------------------
// MFMA core (2 row-tiles of 16): C += A_lds[32 x K] @ W_t[256 x K]^T
// ---------------------------------------------------------------------------
template<int K, int LS>
__device__ __forceinline__ void mfma_core(const unsigned short* __restrict__ As,
                                          const unsigned short* __restrict__ Wt,
                                          f32x4 (&acc)[2][4], int wave, int lane) {
    const int lm = lane & 15, quad = lane >> 4;
    for (int ks = 0; ks < K; ks += 32) {
        short8 af[2], bf[4];
#pragma unroll
        for (int rt = 0; rt < 2; ++rt)
            af[rt] = *(const short8*)&As[(rt * 16 + lm) * LS + ks + quad * 8];
#pragma unroll
        for (int ct = 0; ct < 4; ++ct)
            bf[ct] = *(const short8*)&Wt[(size_t)(wave * 64 + ct * 16 + lm) * K + ks + quad * 8];
#pragma unroll
        for (int rt = 0; rt < 2; ++rt)
#pragma unroll
            for (int ct = 0; ct < 4; ++ct)
                acc[rt][ct] = __builtin_amdgcn_mfma_f32_16x16x32_bf16(af[rt], bf[ct], acc[rt][ct], 0, 0, 0);
    }
}

// Dual-B variant: two GEMMs sharing the same A fragments.
template<int K, int LS>
__device__ __forceinline__ void mfma_core2(const unsigned short* __restrict__ As,
                                           const unsigned short* __restrict__ WtA,
                                           const unsigned short* __restrict__ WtB,
                                           f32x4 (&accA)[2][4], f32x4 (&accB)[2][4],
                                           int wave, int lane) {
    const int lm = lane & 15, quad = lane >> 4;
    for (int ks = 0; ks < K; ks += 32) {
        short8 af[2], bfA[4], bfB[4];
#pragma unroll
        for (int rt = 0; rt < 2; ++rt)
            af[rt] = *(const short8*)&As[(rt * 16 + lm) * LS + ks + quad * 8];
#pragma unroll
        for (int ct = 0; ct < 4; ++ct) {
            size_t off = (size_t)(wave * 64 + ct * 16 + lm) * K + ks + quad * 8;
            bfA[ct] = *(const short8*)&WtA[off];
            bfB[ct] = *(const short8*)&WtB[off];
        }
#pragma unroll
        for (int rt = 0; rt < 2; ++rt)
#pragma unroll
            for (int ct = 0; ct < 4; ++ct) {
                accA[rt][ct] = __builtin_amdgcn_mfma_f32_16x16x32_bf16(af[rt], bfA[ct], accA[rt][ct], 0, 0, 0);
                accB[rt][ct] = __builtin_amdgcn_mfma_f32_16x16x32_bf16(af[rt], bfB[ct], accB[rt][ct], 0, 0, 0);
            }
    }
}

// C-layout acc -> bf16 tile in LDS (rows 0..31, stride LSP)
__device__ __forceinline__ void epi_to_lds(f32x4 (&acc)[2][4],
                                           const float* __restrict__ bias,
                                           bool relu_,
                                           unsigned short* __restrict__ E,
                                           int wave, int lane) {
    const int lm = lane & 15, quad = lane >> 4;
#pragma unroll
    for (int ct = 0; ct < 4; ++ct) {
        int col = wave * 64 + ct * 16 + lm;
        float bv = bias ? bias[col] : 0.f;
#pragma unroll
        for (int rt = 0; rt < 2; ++rt)
#pragma unroll
            for (int i = 0; i < 4; ++i) {
                float v = acc[rt][ct][i] + bv;
                if (relu_) v = fmaxf(v, 0.f);
                E[(rt * 16 + quad * 4 + i) * LSP + col] = f2bf(v);
            }
    }
}

// coalesced 16B row-major store of a 32x256 LDS tile
__device__ __forceinline__ void store_tile32(unsigned short* __restrict__ dst, int base,
                                             const unsigned short* __restrict__ E, int tid) {
#pragma unroll
    for (int k = 0; k < 4; ++k) {
        int j = k * 256 + tid;
        int r = j >> 5, g = j & 31;
        *(short8*)&dst[(size_t)(base + r) * HID + g * 8] = *(const short8*)&E[r * LSP + g * 8];
    }
}

// ---------------------------------------------------------------------------
// k_inp (32-row tiles), 4-barrier schedule, stores never followed by barrier
// except one (aw, overlapped with the KP GEMM):
//   stage |b1| dual GEMM KI |epi mT->wA, aw->wB| b2
//   GEMM KP(wA)+KB; store aw(wB) |b3| epi P0->wA, inp2->wB |b4| store both.
// ---------------------------------------------------------------------------
__global__ __launch_bounds__(256, 4) void k_inp(const float* __restrict__ atom,
                                                const unsigned short* __restrict__ bondsum,
                                                const unsigned short* __restrict__ Wi_t,
                                                const unsigned short* __restrict__ Wb_t,
                                                const unsigned short* __restrict__ Whm_t,
                                                const unsigned short* __restrict__ Woa_t,
                                                const float* __restrict__ bi,
                                                const float* __restrict__ b_ih,
                                                const float* __restrict__ bo,
                                                unsigned short* __restrict__ P0,
                                                unsigned short* __restrict__ inp2,
                                                unsigned short* __restrict__ aw) {
    __shared__ unsigned short atomT[32 * LSI];   // 10.5 KB
    __shared__ unsigned short bs[32 * LSB];      // 2.5 KB
    __shared__ unsigned short wA[32 * LSP];      // 16.5 KB
    __shared__ unsigned short wB[32 * LSP];      // 16.5 KB
    const int tid  = threadIdx.x;
    const int base = blockIdx.x * 32;

    for (int it = tid; it < 32 * KI; it += 256) {
        int r = it / KI, c = it - r * KI;
        atomT[r * LSI + c] = f2bf(c < AF ? atom[(size_t)(base + r) * AF + c] : 0.f);
    }
    if (tid < 128) {
        int r = tid >> 2, c = (tid & 3) * 8;
        *(short8*)&bs[r * LSB + c] = *(const short8*)&bondsum[(size_t)(base + r) * 32 + c];
    }
    __syncthreads();                                    // b1

    const int lane = tid & 63, wave = tid >> 6;
    f32x4 acc1[2][4] = {}, acc3[2][4] = {};
    mfma_core2<KI, LSI>(atomT, Wi_t, Woa_t, acc1, acc3, wave, lane);

    epi_to_lds(acc1, bi, true, wA, wave, lane);         // mT = relu(inp)
    epi_to_lds(acc3, bo, false, wB, wave, lane);        // aw tile
    __syncthreads();                                    // b2

    f32x4 acc2[2][4] = {};
    mfma_core<KP, LSP>(wA, Whm_t, acc2, wave, lane);    // P0 = m @ Whm
    mfma_core<KB, LSB>(bs, Wb_t, acc1, wave, lane);     // + bond part
    store_tile32(aw, base, wB, tid);                    // overlaps the GEMMs
    __syncthreads();                                    // b3 (drains aw)

    epi_to_lds(acc2, nullptr, false, wA, wave, lane);   // P0 tile
    epi_to_lds(acc1, b_ih, false, wB, wave, lane);      // inp2 tile
    __syncthreads();                                    // b4
    store_tile32(P0,   base, wA, tid);
    store_tile32(inp2, base, wB, tid);                  // no barrier after
}

// ---------------------------------------------------------------------------
// k_it (fused gather+proj, 32-row tiles), 3 barriers, final store unbarriered:
//   nb |b1| gather->mT |b2| GEMM; epi->E |b3| store E.
// ---------------------------------------------------------------------------
__global__ __launch_bounds__(256, 4) void k_it(const unsigned short* __restrict__ Pin,
                                               const unsigned short* __restrict__ base_,
                                               const int* __restrict__ a2a,
                                               const unsigned short* __restrict__ Wt,
                                               unsigned short* __restrict__ Pout) {
    __shared__ unsigned short mT[32 * LSP];   // 16.5 KB
    __shared__ unsigned short E[32 * LSP];    // 16.5 KB
    __shared__ int nb_l[32 * NNB];
    const int tid  = threadIdx.x;
    const int base = blockIdx.x * 32;

    if (tid < 32 * NNB) nb_l[tid] = a2a[base * NNB + tid];
    __syncthreads();                                    // b1

#pragma unroll 2
    for (int k = 0; k < 4; ++k) {
        int j = k * 256 + tid;
        int r = j >> 5, g = j & 31;
        const int* nb = &nb_l[r * NNB];
        float s[8] = {};
#pragma unroll
        for (int t = 0; t < NNB; ++t) {
            short8 u = *(const short8*)&Pin[(size_t)nb[t] * HID + g * 8];
#pragma unroll
            for (int q = 0; q < 8; ++q) s[q] += bf2f((unsigned short)u[q]);
        }
        short8 b = *(const short8*)&base_[(size_t)(base + r) * HID + g * 8];
        short8 o;
#pragma unroll
        for (int q = 0; q < 8; ++q)
            o[q] = (short)f2bf(fmaxf(s[q] + bf2f((unsigned short)b[q]), 0.f));
        *(short8*)&mT[r * LSP + g * 8] = o;
    }
    __syncthreads();                                    // b2

    const int lane = tid & 63, wave = tid >> 6;
    f32x4 acc[2][4] = {};
    mfma_core<KP, LSP>(mT, Wt, acc, wave, lane);
    epi_to_lds(acc, nullptr, false, E, wave, lane);
    __syncthreads();                                    // b3
    store_tile32(Pout, base, E, tid);                   // no barrier after
}

// ---------------------------------------------------------------------------
// k_gseg (fused final gather + segment mean): one block per molecule.
// 8 row-slots x 32 col-groups; short8 loads; LDS partial reduce.
// ---------------------------------------------------------------------------
__global__ __launch_bounds__(256, 6) void k_gseg(const unsigned short* __restrict__ P,
                                                 const unsigned short* __restrict__ aw,
                                                 const int* __restrict__ a2a,
                                                 const int* __restrict__ seg,
                                                 float* __restrict__ out) {
    const int m = blockIdx.x;
    __shared__ int lohi[2];
    __shared__ float red[8 * 256];   // 8 KB
    if (threadIdx.x == 0) {
        int lo = 0, hi = N_ATOMS;
        while (lo < hi) { int mid = (lo + hi) >> 1; if (seg[mid] < m) lo = mid + 1; else hi = mid; }
        lohi[0] = lo;
        int lo2 = lo, hi2 = N_ATOMS;
        while (lo2 < hi2) { int mid = (lo2 + hi2) >> 1; if (seg[mid] < m + 1) lo2 = mid + 1; else hi2 = mid; }
        lohi[1] = lo2;
    }
    __syncthreads();
    const int lo = lohi[0], hi = lohi[1];
    const int slot = threadIdx.x >> 5;
    const int cg   = threadIdx.x & 31;

    float s[8] = {};
#pragma unroll 1
    for (int i0 = lo; i0 < hi; i0 += 8) {
        int i = i0 + slot;
        if (i < hi) {
            const int* nb = &a2a[i * NNB];
            short8 a = *(const short8*)&aw[(size_t)i * HID + cg * 8];
            float v[8];
#pragma unroll
            for (int q = 0; q < 8; ++q) v[q] = bf2f((unsigned short)a[q]);
#pragma unroll
            for (int t = 0; t < NNB; ++t) {
                short8 u = *(const short8*)&P[(size_t)nb[t] * HID + cg * 8];
#pragma unroll
                for (int q = 0; q < 8; ++q) v[q] += bf2f((unsigned short)u[q]);
            }
#pragma unroll
            for (int q = 0; q < 8; ++q) s[q] += fmaxf(v[q], 0.f);
        }
    }
#pragma unroll
    for (int q = 0; q < 8; ++q) red[slot * 256 + cg * 8 + q] = s[q];
    __syncthreads();

    const int j = threadIdx.x;
    float tot = 0.f;
#pragma unroll
    for (int sl = 0; sl < 8; ++sl) tot += red[sl * 256 + j];
    const int cnt = hi - lo;
    out[m * HID + j] = (cnt > 0) ? (tot / (float)cnt) : 0.f;
}

// ---------------------------------------------------------------------------
extern "C" void kernel_launch(void* const* d_in, const int* in_sizes, int n_in,
                              void* d_out, int out_size, void* d_ws, size_t ws_size,
                              hipStream_t stream) {
    const float* atom    = (const float*)d_in[0];
    const float* f_bonds = (const float*)d_in[1];
    const int*   a2a     = (const int*)d_in[2];
    const int*   a2b     = (const int*)d_in[3];
    const int*   seg     = (const int*)d_in[4];
    const float* Wi      = (const float*)d_in[5];
    const float* bi      = (const float*)d_in[6];
    const float* Wh      = (const float*)d_in[7];
    const float* bh      = (const float*)d_in[8];
    const float* Wo      = (const float*)d_in[9];
    const float* bo      = (const float*)d_in[10];
    float* out = (float*)d_out;

    unsigned short* ws = (unsigned short*)d_ws;
    const size_t nh = (size_t)N_ATOMS * HID;
    unsigned short* Pa   = ws;               // 32 MB
    unsigned short* Pb   = Pa + nh;          // 32 MB
    unsigned short* inp2 = Pb + nh;          // 32 MB
    unsigned short* aw   = inp2 + nh;        // 32 MB
    unsigned short* bsum = aw + nh;          // 4 MB
    unsigned short* Wi_t  = bsum + (size_t)N_ATOMS * 32;
    unsigned short* Wb_t  = Wi_t + 256 * KI;
    unsigned short* Whm_t = Wb_t + 256 * KB;
    unsigned short* Woa_t = Whm_t + 256 * KP;
    unsigned short* Wom_t = Woa_t + 256 * KI;
    float*          b_ih  = (float*)(Wom_t + 256 * KP);

    dim3 blk(256);
    const int nb32 = N_ATOMS / 32;   // 2048

    k_prep_bond<<<256 + N_ATOMS * 16 / 256, blk, 0, stream>>>(
        Wi, Wh, Wo, bi, bh, f_bonds, a2b,
        Wi_t, Wb_t, Whm_t, Woa_t, Wom_t, bsum, b_ih);
    k_inp<<<nb32, blk, 0, stream>>>(atom, bsum, Wi_t, Wb_t, Whm_t, Woa_t,
                                    bi, b_ih, bo, Pa, inp2, aw);

    k_it<<<nb32, blk, 0, stream>>>(Pa, inp2, a2a, Whm_t, Pb);   // -> P1
    k_it<<<nb32, blk, 0, stream>>>(Pb, inp2, a2a, Wom_t, Pa);   // -> P2
    k_gseg<<<NM, blk, 0, stream>>>(Pa, aw, a2a, seg, out);
}